// Round 6
// baseline (79.893 us; speedup 1.0000x reference)
//
#include <hip/hip_runtime.h>

#define L2E  1.4426950408889634f
#define LN2f 0.6931471805599453f

template<int CTRL>
__device__ __forceinline__ float dppf(float x) {
  int r = __builtin_amdgcn_update_dpp(0, __builtin_bit_cast(int, x), CTRL, 0xF, 0xF, true);
  return __builtin_bit_cast(float, r);
}
template<int CTRL>
__device__ __forceinline__ int dppi(int x) {
  return __builtin_amdgcn_update_dpp(0, x, CTRL, 0xF, 0xF, true);
}

// xor-16 exchange within each 32-lane group (ds_swizzle BitMode: and=0x1F, xor=0x10)
__device__ __forceinline__ float swz16(float x) {
  return __builtin_bit_cast(float,
      __builtin_amdgcn_ds_swizzle(__builtin_bit_cast(int, x), 0x401F));
}

// max over a 16-lane row via DPP butterfly (ctrl set verified R2/R4/R5, absmax 0)
__device__ __forceinline__ float bflymax16(float x) {
  x = fmaxf(x, dppf<0xB1>(x));    // lane^1
  x = fmaxf(x, dppf<0x4E>(x));    // lane^2
  x = fmaxf(x, dppf<0x141>(x));   // lane^7
  x = fmaxf(x, dppf<0x140>(x));   // lane^15
  return x;
}

// Half-split rotate-and-dot: half h applies rotations ror(8h+k), k=0..7, to shv
// (h=1 pre-rotates by ror8; ror composes additively). Partials from the two
// halves combine via one swizzle. Wr built with the IDENTICAL op sequence on
// lane indices, so the rotation-direction convention cancels (direction-proof).
#define DOT(shv, tot) {                                   \
    const float b_ = hsel ? dppf<0x128>(shv) : (shv);     \
    float t0_ = b_ * Wr[0];                               \
    float t1_ = dppf<0x121>(b_) * Wr[1];                  \
    t0_ = fmaf(dppf<0x122>(b_), Wr[2], t0_);              \
    t1_ = fmaf(dppf<0x123>(b_), Wr[3], t1_);              \
    t0_ = fmaf(dppf<0x124>(b_), Wr[4], t0_);              \
    t1_ = fmaf(dppf<0x125>(b_), Wr[5], t1_);              \
    t0_ = fmaf(dppf<0x126>(b_), Wr[6], t0_);              \
    t1_ = fmaf(dppf<0x127>(b_), Wr[7], t1_);              \
    const float part_ = t0_ + t1_;                        \
    tot = part_ + swz16(part_); }

// One direction's scan (math identical to R4/R5, absmax 0). fwd: t=1..255,
// v_t = mask ? diag(p_t)·W^T·v : v.  bwd: t=511..256, u' = mask ? W·(p∘u) : u.
// Linear-pointer 8-deep prefetch; over-reads stay in-bounds (fwd<=263, bwd>=248).
template<bool BWD>
__device__ __forceinline__ void scan(const float* __restrict__ ep,
                                     const int* __restrict__ ys,
                                     const float (&Wr)[8], bool hsel,
                                     int j, int jm,
                                     float& ownO, float& MO, float& eaccO) {
  float own, M, eacc;
  float ebuf[8]; int ybuf[8];
  const float* pe;
  const int* py;
  if (!BWD) {
    const float a0 = ep[0];
    const int y0 = ys[0];
    eacc = (y0 == jm) ? a0 : 0.f;
    const float A = (j < 15) ? a0 * L2E : -1.0e30f;
    const float M0 = bflymax16(A);
    own = exp2f(A - M0);
    M = M0;
    #pragma unroll
    for (int i = 0; i < 8; ++i) { ebuf[i] = ep[(1 + i) * 15]; ybuf[i] = ys[1 + i]; }
    pe = ep + 9 * 15;
    py = ys + 9;
  } else {
    eacc = 0.f;
    own = (j < 15) ? 1.f : 0.f;
    M = 0.f;
    #pragma unroll
    for (int i = 0; i < 8; ++i) { ebuf[i] = ep[(511 - i) * 15]; ybuf[i] = ys[511 - i]; }
    pe = ep + (511 - 8) * 15;
    py = ys + (511 - 8);
  }

  if (!BWD) {
    for (int sb = 0; sb < 31; ++sb) {          // t = 1..248
      #pragma unroll
      for (int k = 0; k < 8; ++k) {
        const float emit = ebuf[k]; const int yv = ybuf[k];
        ebuf[k] = *pe; pe += 15;
        ybuf[k] = *py; py += 1;
        const float p = exp2f(emit * L2E);
        float tot; DOT(own, tot);
        const float cand = tot * p;
        own = (yv != 15) ? cand : own;
        eacc += (yv == jm) ? emit : 0.f;
        if (k == 7) {
          const float m = bflymax16(own);
          own *= __builtin_amdgcn_rcpf(m);
          M += log2f(m);
        }
      }
    }
    #pragma unroll
    for (int k = 0; k < 7; ++k) {              // t = 249..255
      const float emit = ebuf[k]; const int yv = ybuf[k];
      ebuf[k] = *pe; pe += 15;                 // harmless over-prefetch (t<=263)
      const float p = exp2f(emit * L2E);
      float tot; DOT(own, tot);
      const float cand = tot * p;
      own = (yv != 15) ? cand : own;
      eacc += (yv == jm) ? emit : 0.f;
    }
  } else {
    for (int sb = 0; sb < 32; ++sb) {          // t = 511..256
      #pragma unroll
      for (int k = 0; k < 8; ++k) {
        const float emit = ebuf[k]; const int yv = ybuf[k];
        ebuf[k] = *pe; pe -= 15;               // over-prefetch down to t=248
        ybuf[k] = *py; py -= 1;
        const float p = exp2f(emit * L2E);
        const float share = own * p;
        float tot; DOT(share, tot);
        own = (yv != 15) ? tot : own;
        eacc += (yv == jm) ? emit : 0.f;
        if (k == 7) {
          const float m = bflymax16(own);
          own *= __builtin_amdgcn_rcpf(m);
          M += log2f(m);
        }
      }
    }
  }
  ownO = own; MO = M; eaccO = eacc;
}

__global__ __launch_bounds__(256, 4)
void crf_rot32(const float* __restrict__ logits, const int* __restrict__ yg,
               const float* __restrict__ trans, float* __restrict__ out) {
  __shared__ float Tl[240];
  __shared__ int   yl[4 * 520];    // padded per-seq stride (bank de-alias)
  __shared__ float comb[4][2][16];
  __shared__ float pathE[4][2];
  __shared__ float transS[4];
  __shared__ float blks[4];

  const int tid = threadIdx.x;
  if (tid < 225) Tl[tid] = trans[tid];
  {
    // stage 4 seqs x 512 ints, per-seq stride 130 int4 = 520 ints
    const int4* src = (const int4*)(yg + (size_t)blockIdx.x * 2048);
    int4* dst = (int4*)yl;
    #pragma unroll
    for (int k = 0; k < 2; ++k) {
      const int g = tid + k * 256;             // 0..511
      const int sq = g >> 7, pos = g & 127;
      dst[sq * 130 + pos] = src[g];
    }
  }
  __syncthreads();

  // ---- transition part of path score (LDS-only; 64 threads/seq, t=1..511) ----
  {
    const int q = tid >> 6, l64 = tid & 63;
    const int* ys = yl + q * 520;
    float acc = 0.f;
    #pragma unroll
    for (int m = 0; m < 8; ++m) {
      const int t = 1 + l64 + 64 * m;
      if (t < 512) {
        const int yc = ys[t], yp = ys[t - 1];
        if (yc < 15 && yp < 15) acc += Tl[yp * 15 + yc];
      }
    }
    #pragma unroll
    for (int k = 1; k < 64; k <<= 1) acc += __shfl_xor(acc, k, 64);
    if (l64 == 0) transS[q] = acc;
  }

  // ---- chain setup: 32 lanes/chain, 2 chains/wave; whole wave is fwd or bwd ----
  const int wave = tid >> 6, lane = tid & 63;
  const int c = lane >> 5;                 // chain within wave
  const bool hsel = ((lane >> 4) & 1) != 0; // rotation half
  const int j = lane & 15;
  const int sLoc = (wave >> 1) * 2 + c;    // 0..3
  const bool isFwd = (wave & 1) == 0;
  const int seq = blockIdx.x * 4 + sLoc;
  const int jj = (j < 15) ? j : 14;
  const int jm = (j < 15) ? j : 255;
  const float* ep = logits + (size_t)seq * 7680 + jj;
  const int* ys = yl + sLoc * 520;

  // Wr[k] = exp(T[src][j]) (fwd) / exp(T[j][src]) (bwd), src derived by the
  // SAME composed DPP ops applied to the lane index (direction-proof).
  const int jr8 = dppi<0x128>(j);
  const int hb = hsel ? jr8 : j;
  float Wr[8];
  {
    const int s_ = hb;
    const bool v_ = (j < 15) && (s_ < 15);
    const int ix_ = isFwd ? s_ * 15 + j : j * 15 + s_;
    Wr[0] = v_ ? exp2f(Tl[v_ ? ix_ : 0] * L2E) : 0.f;
  }
#define SETW(K) { const int s_ = dppi<0x120 + (K)>(hb);                 \
    const bool v_ = (j < 15) && (s_ < 15);                              \
    const int ix_ = isFwd ? s_ * 15 + j : j * 15 + s_;                  \
    Wr[K] = v_ ? exp2f(Tl[v_ ? ix_ : 0] * L2E) : 0.f; }
  SETW(1) SETW(2) SETW(3) SETW(4) SETW(5) SETW(6) SETW(7)
#undef SETW
  // Pin Wr in VGPRs (R5: prevents in-loop rematerialization of exp2(Tl[...]))
  #pragma unroll
  for (int r = 0; r < 8; ++r) asm volatile("" : "+v"(Wr[r]));

  float own, M, eacc;
  if (isFwd) scan<false>(ep, ys, Wr, hsel, j, jm, own, M, eacc);
  else       scan<true >(ep, ys, Wr, hsel, j, jm, own, M, eacc);

  const int dir = isFwd ? 0 : 1;
  if (!hsel && j < 15) comb[sLoc][dir][j] = M + log2f(own);
  #pragma unroll
  for (int k = 1; k < 16; k <<= 1) eacc += __shfl_xor(eacc, k, 16);
  if (!hsel && j == 0) pathE[sLoc][dir] = eacc;

  __syncthreads();

  // ---- per-sequence combine: logZ = lse_i(log v_255[i] + log u_255[i]) ----
  if (tid < 4) {
    float mx = -3.0e38f; float s[15];
    #pragma unroll
    for (int i = 0; i < 15; ++i) {
      s[i] = comb[tid][0][i] + comb[tid][1][i];
      mx = fmaxf(mx, s[i]);
    }
    float sum = 0.f;
    #pragma unroll
    for (int i = 0; i < 15; ++i) sum += exp2f(s[i] - mx);
    const float logZ = (mx + log2f(sum)) * LN2f;
    const float path = pathE[tid][0] + pathE[tid][1] + transS[tid];
    float nll = logZ - path;
    nll = fminf(fmaxf(nll, 0.f), 1000000.f);
    blks[tid] = nll;
  }
  __syncthreads();
  if (tid == 0) {
    const float tot = (blks[0] + blks[1]) + (blks[2] + blks[3]);
    atomicAdd(out, tot * (1.0f / 4096.0f));
  }
}

extern "C" void kernel_launch(void* const* d_in, const int* in_sizes, int n_in,
                              void* d_out, int out_size, void* d_ws, size_t ws_size,
                              hipStream_t stream) {
  const float* logits = (const float*)d_in[0];   // (4096, 512, 15) f32
  const int*   y      = (const int*)d_in[1];     // (4096, 512) i32
  const float* trans  = (const float*)d_in[2];   // (15, 15) f32
  float* out = (float*)d_out;

  hipMemsetAsync(out, 0, sizeof(float), stream);

  const int B = in_sizes[1] / 512;               // 4096
  crf_rot32<<<dim3(B / 4), dim3(256), 0, stream>>>(logits, y, trans, out);
}